// Round 11
// baseline (57.712 us; speedup 1.0000x reference)
//
#include <hip/hip_runtime.h>

// Fully-fused 4-layer MLP via f16 MFMA (fp32 accumulate), transposed problem
// G = H^T: activations live in registers across all layers (B operand).
// R11 = R10 (S=2: 64 samples/wave, every LDS A-read feeds 2 MFMAs, 4 acc
// chains/phase, grid 512 = 2 blocks/CU) with ONE change: amdgpu_waves_per_eu
// (2,2) (min=max) so the allocator uses the full 256-VGPR budget instead of
// capping at 128 and spilling (R10's failure: FETCH 25MB/WRITE 76MB spill
// traffic). R9 proved true S=2 demand = 240 VGPR, which fits 2 waves/SIMD.

typedef _Float16 half_t;
typedef _Float16 half8 __attribute__((ext_vector_type(8)));
typedef float f32x16 __attribute__((ext_vector_type(16)));
typedef unsigned int uint4v __attribute__((ext_vector_type(4)));
typedef int int2v __attribute__((ext_vector_type(2)));

#define M_TOTAL (64*2048)

// ---------------- prep kernel ----------------
// Fragment-block layout (512 halves per block), nt-major within each layer:
//   L1: blocks 0..7     (nt, ks=0; K padded 13->16)
//   L2: blocks 8..135   (nt*16 + ks)
//   L3: blocks 136..263 (nt*16 + ks)
//   L4: blocks 264..311 (nt*16 + ks; N padded 80->96)
// Within a block: wp[blk*512 + lane*8 + j] = W[ks*16 + (lane>>5)*8 + j][nt*32 + (lane&31)]
__global__ void prep_w(const float* __restrict__ W1, const float* __restrict__ W2,
                       const float* __restrict__ W3, const float* __restrict__ W4,
                       half_t* __restrict__ wp) {
    int tid = blockIdx.x * 256 + threadIdx.x;
    if (tid >= 312 * 512) return;
    int blk = tid >> 9, r = tid & 511;
    int lane = r >> 3, j = r & 7;
    const float* W; int K, N, nt, ks;
    if (blk < 8)        { W = W1; K = 13;  N = 256; nt = blk;              ks = 0; }
    else if (blk < 136) { W = W2; K = 256; N = 256; nt = (blk-8) >> 4;     ks = (blk-8) & 15; }
    else if (blk < 264) { W = W3; K = 256; N = 256; nt = (blk-136) >> 4;   ks = (blk-136) & 15; }
    else                { W = W4; K = 256; N = 80;  nt = (blk-264) >> 4;   ks = (blk-264) & 15; }
    int k = ks * 16 + (lane >> 5) * 8 + j;
    int n = nt * 32 + (lane & 31);
    float v = (k < K && n < N) ? W[k * N + n] : 0.f;
    wp[tid] = (half_t)v;
}

// ---------------- main kernel ----------------

__device__ __forceinline__ unsigned int pkrtz(float a, float b) {
    auto p = __builtin_amdgcn_cvt_pkrtz(a, b);
    return __builtin_bit_cast(unsigned int, p);
}

typedef const __attribute__((address_space(1))) unsigned int guint_t;
typedef __attribute__((address_space(3))) unsigned int luint_t;

// Stage `bytes` (multiple of 4096) from g into LDS l. 256 threads x 16 B.
__device__ __forceinline__ void stage_strip(const half_t* __restrict__ g,
                                            half_t* l, int bytes, int tid) {
    const char* gc = (const char*)g;
    char* lc = (char*)l;
    const int go = tid * 16;             // per-lane global offset
    const int lo = (tid >> 6) << 10;     // wave-uniform LDS offset (wave*1024)
#pragma unroll
    for (int r = 0; r < bytes; r += 4096) {
        __builtin_amdgcn_global_load_lds((guint_t*)(gc + r + go),
                                         (luint_t*)(lc + r + lo), 16, 0, 0);
    }
}

// strip index (0..10) -> offset in wp (halves). 0:L1 8KB; 1-4:L2 32KB;
// 5-8:L3 32KB; 9:L4 nt{0,1} 32KB; 10:L4 nt2 16KB.
__device__ __forceinline__ int strip_off(int s) {
    if (s == 0)  return 0;
    if (s <= 4)  return (8   + (s - 1) * 32) * 512;
    if (s <= 8)  return (136 + (s - 5) * 32) * 512;
    if (s == 9)  return 264 * 512;
    return 296 * 512;
}

// Repack one C-fragment s-group into 4 B-words (both lane halves).
template <bool RELU>
__device__ __forceinline__ void repack_s(const f32x16& acc, int s,
                                         const float* biasnt, bool hi,
                                         unsigned int* Bw)
{
    float v[8];
#pragma unroll
    for (int q = 0; q < 8; ++q) {
        // C row = (reg&3) + 8*(reg>>2) + 4*(lane>=32), reg = 8s+q
        int f = (q & 3) + 8 * (q >> 2) + (hi ? 4 : 0);
        float t = acc[8 * s + q] + biasnt[16 * s + f];
        v[q] = RELU ? fmaxf(t, 0.f) : t;
    }
    unsigned int P0 = pkrtz(v[0], v[1]);   // lo:(0,1)  hi:(4,5)
    unsigned int P1 = pkrtz(v[2], v[3]);   // lo:(2,3)  hi:(6,7)
    unsigned int P2 = pkrtz(v[4], v[5]);   // lo:(8,9)  hi:(12,13)
    unsigned int P3 = pkrtz(v[6], v[7]);   // lo:(10,11) hi:(14,15)
    // One swap fills two B-words: word0=[P0.lo|P2.lo], word2=[P0.hi|P2.hi]
    int2v r02 = __builtin_amdgcn_permlane32_swap((int)P0, (int)P2, false, false);
    int2v r13 = __builtin_amdgcn_permlane32_swap((int)P1, (int)P3, false, false);
    Bw[0] = (unsigned int)r02.x;
    Bw[1] = (unsigned int)r13.x;
    Bw[2] = (unsigned int)r02.y;
    Bw[3] = (unsigned int)r13.y;
}

#define MFMA16(a, b, c) __builtin_amdgcn_mfma_f32_32x32x16_f16((a), (b), (c), 0, 0, 0)

__device__ __forceinline__ half8 bw_cast(const unsigned int* w) {
    uint4v t = { w[0], w[1], w[2], w[3] };
    return __builtin_bit_cast(half8, t);
}

// One 32KB strip phase (2 nt tiles), both sample groups: 4 acc chains.
template <bool RELU>
__device__ __forceinline__ void dense_phase(const half_t* sb,
                                            const unsigned int (&Bin)[2][16][4],
                                            unsigned int (&Bout)[2][16][4],
                                            int ntbase, const float* biasL,
                                            int lane, bool hi)
{
    f32x16 acc00 = {}, acc01 = {}, acc10 = {}, acc11 = {};
    __builtin_amdgcn_s_setprio(1);
#pragma unroll
    for (int ks = 0; ks < 16; ++ks) {
        half8 a0 = *(const half8*)(sb + ((ks * 64 + lane) << 3));
        half8 a1 = *(const half8*)(sb + 16 * 512 + ((ks * 64 + lane) << 3));
        half8 b0 = bw_cast(Bin[0][ks]);
        half8 b1 = bw_cast(Bin[1][ks]);
        acc00 = MFMA16(a0, b0, acc00);
        acc01 = MFMA16(a0, b1, acc01);
        acc10 = MFMA16(a1, b0, acc10);
        acc11 = MFMA16(a1, b1, acc11);
    }
    __builtin_amdgcn_s_setprio(0);
#pragma unroll
    for (int s = 0; s < 2; ++s) {
        repack_s<RELU>(acc00, s, biasL + ntbase * 32, hi, Bout[0][2 * ntbase + s]);
        repack_s<RELU>(acc01, s, biasL + ntbase * 32, hi, Bout[1][2 * ntbase + s]);
        repack_s<RELU>(acc10, s, biasL + (ntbase + 1) * 32, hi, Bout[0][2 * (ntbase + 1) + s]);
        repack_s<RELU>(acc11, s, biasL + (ntbase + 1) * 32, hi, Bout[1][2 * (ntbase + 1) + s]);
    }
}

// L4 strip9 phase: nt 0,1 for both groups, direct global stores.
__device__ __forceinline__ void out_phase2(const half_t* sb,
                                           const unsigned int (&Bin)[2][16][4],
                                           const float* bias4, float* __restrict__ out,
                                           int mb, int lane, bool hi)
{
    f32x16 acc00 = {}, acc01 = {}, acc10 = {}, acc11 = {};
    __builtin_amdgcn_s_setprio(1);
#pragma unroll
    for (int ks = 0; ks < 16; ++ks) {
        half8 a0 = *(const half8*)(sb + ((ks * 64 + lane) << 3));
        half8 a1 = *(const half8*)(sb + 16 * 512 + ((ks * 64 + lane) << 3));
        half8 b0 = bw_cast(Bin[0][ks]);
        half8 b1 = bw_cast(Bin[1][ks]);
        acc00 = MFMA16(a0, b0, acc00);
        acc01 = MFMA16(a0, b1, acc01);
        acc10 = MFMA16(a1, b0, acc10);
        acc11 = MFMA16(a1, b1, acc11);
    }
    __builtin_amdgcn_s_setprio(0);
#pragma unroll
    for (int ntL = 0; ntL < 2; ++ntL) {
#pragma unroll
        for (int g = 0; g < 2; ++g) {
            const f32x16& acc = ntL == 0 ? (g == 0 ? acc00 : acc01)
                                         : (g == 0 ? acc10 : acc11);
            float* orow = out + (long)(mb + g * 32 + (lane & 31)) * 80 + ntL * 32;
#pragma unroll
            for (int reg = 0; reg < 16; ++reg) {
                int rr = (reg & 3) + 8 * (reg >> 2) + (hi ? 4 : 0);
                orow[rr] = acc[reg] + bias4[ntL * 32 + rr];
            }
        }
    }
}

// L4 strip10 phase: nt2 (features 64..79 only).
__device__ __forceinline__ void out_phase1(const half_t* sb,
                                           const unsigned int (&Bin)[2][16][4],
                                           const float* bias42, float* __restrict__ out,
                                           int mb, int lane, bool hi)
{
    f32x16 acc0 = {}, acc1 = {};
    __builtin_amdgcn_s_setprio(1);
#pragma unroll
    for (int ks = 0; ks < 16; ++ks) {
        half8 a = *(const half8*)(sb + ((ks * 64 + lane) << 3));
        acc0 = MFMA16(a, bw_cast(Bin[0][ks]), acc0);
        acc1 = MFMA16(a, bw_cast(Bin[1][ks]), acc1);
    }
    __builtin_amdgcn_s_setprio(0);
#pragma unroll
    for (int g = 0; g < 2; ++g) {
        const f32x16& acc = g == 0 ? acc0 : acc1;
        float* orow = out + (long)(mb + g * 32 + (lane & 31)) * 80 + 64;
#pragma unroll
        for (int reg = 0; reg < 8; ++reg) {          // rr < 16 <=> f < 80
            int rr = (reg & 3) + 8 * (reg >> 2) + (hi ? 4 : 0);
            orow[rr] = acc[reg] + bias42[rr];
        }
    }
}

__global__ __attribute__((amdgpu_flat_work_group_size(256, 256), amdgpu_waves_per_eu(2, 2)))
void mlp_mfma(
    const float* __restrict__ x, const half_t* __restrict__ wp,
    const float* __restrict__ b1, const float* __restrict__ b2,
    const float* __restrict__ b3, const float* __restrict__ b4,
    float* __restrict__ out)
{
    __shared__ half_t wbuf[2][16384];    // 2 x 32 KB strip double-buffer
    __shared__ float  bias_lds[864];     // b1|b2|b3 (256 each) | b4 (96, padded)

    const int tid  = threadIdx.x;
    const int lane = tid & 63;
    const int wave = tid >> 6;
    const bool hi  = lane >= 32;
    const int mb   = blockIdx.x * 256 + wave * 64;   // 64 samples per wave

    stage_strip(wp + strip_off(0), wbuf[0], 8192, tid);    // L1 strip -> buf0

    bias_lds[tid] = b1[tid];
    bias_lds[256 + tid] = b2[tid];
    bias_lds[512 + tid] = b3[tid];
    if (tid < 96) bias_lds[768 + tid] = (tid < 80) ? b4[tid] : 0.f;

    // Layer-1 B fragments from fp32 x: lane holds x[m][k], k = (hi?8:0)+j
    unsigned int Bx[2][4];
#pragma unroll
    for (int g = 0; g < 2; ++g) {
        const float* xp = x + (long)(mb + g * 32 + (lane & 31)) * 13;
        float xv[8];
        if (!hi) {
#pragma unroll
            for (int j = 0; j < 8; ++j) xv[j] = xp[j];
        } else {
#pragma unroll
            for (int j = 0; j < 5; ++j) xv[j] = xp[8 + j];
            xv[5] = xv[6] = xv[7] = 0.f;
        }
        Bx[g][0] = pkrtz(xv[0], xv[1]);
        Bx[g][1] = pkrtz(xv[2], xv[3]);
        Bx[g][2] = pkrtz(xv[4], xv[5]);
        Bx[g][3] = pkrtz(xv[6], xv[7]);
    }

    __syncthreads();   // bias + strip0 resident (drains vmcnt)

    unsigned int BA[2][16][4], BB[2][16][4];

    // ---- Phase 0 / L1: strip0 (8 nt, ks=0), 13->256 ----
    {
        stage_strip(wp + strip_off(1), wbuf[1], 32768, tid);
        __builtin_amdgcn_sched_barrier(0);
        const half_t* sb = &wbuf[0][0];
        half8 bx0 = bw_cast(Bx[0]);
        half8 bx1 = bw_cast(Bx[1]);
#pragma unroll
        for (int nt = 0; nt < 8; ++nt) {
            half8 a = *(const half8*)(sb + nt * 512 + (lane << 3));
            f32x16 acc0 = {}, acc1 = {};
            acc0 = MFMA16(a, bx0, acc0);
            acc1 = MFMA16(a, bx1, acc1);
#pragma unroll
            for (int s = 0; s < 2; ++s) {
                repack_s<true>(acc0, s, bias_lds + nt * 32, hi, BB[0][2 * nt + s]);
                repack_s<true>(acc1, s, bias_lds + nt * 32, hi, BB[1][2 * nt + s]);
            }
        }
        __syncthreads();
    }

    // ---- Phases 1..4 / L2: strips 1..4 (2 nt each), 256->256 ----
#pragma unroll
    for (int i = 0; i < 4; ++i) {
        const int p = 1 + i;
        stage_strip(wp + strip_off(p + 1), wbuf[(p + 1) & 1], 32768, tid);
        __builtin_amdgcn_sched_barrier(0);
        dense_phase<true>(&wbuf[p & 1][0], BB, BA, 2 * i, bias_lds + 256, lane, hi);
        __syncthreads();
    }

    // ---- Phases 5..8 / L3: strips 5..8, 256->256 ----
#pragma unroll
    for (int i = 0; i < 4; ++i) {
        const int p = 5 + i;
        stage_strip(wp + strip_off(p + 1), wbuf[(p + 1) & 1],
                    (p + 1 == 10) ? 16384 : 32768, tid);
        __builtin_amdgcn_sched_barrier(0);
        dense_phase<true>(&wbuf[p & 1][0], BA, BB, 2 * i, bias_lds + 512, lane, hi);
        __syncthreads();
    }

    // ---- Phase 9 / L4 nt{0,1}: strip9 (in wbuf[1]), direct stores ----
    {
        stage_strip(wp + strip_off(10), wbuf[0], 16384, tid);
        __builtin_amdgcn_sched_barrier(0);
        out_phase2(&wbuf[1][0], BB, bias_lds + 768, out, mb, lane, hi);
        __syncthreads();
    }

    // ---- Phase 10 / L4 nt2: strip10 (in wbuf[0]) ----
    out_phase1(&wbuf[0][0], BB, bias_lds + 768 + 64, out, mb, lane, hi);
}

// ---------------- launch ----------------

extern "C" void kernel_launch(void* const* d_in, const int* in_sizes, int n_in,
                              void* d_out, int out_size, void* d_ws, size_t ws_size,
                              hipStream_t stream) {
    const float* x  = (const float*)d_in[0];
    const float* W1 = (const float*)d_in[1];
    const float* b1 = (const float*)d_in[2];
    const float* W2 = (const float*)d_in[3];
    const float* b2 = (const float*)d_in[4];
    const float* W3 = (const float*)d_in[5];
    const float* b3 = (const float*)d_in[6];
    const float* W4 = (const float*)d_in[7];
    const float* b4 = (const float*)d_in[8];
    float* out = (float*)d_out;

    half_t* wp = (half_t*)d_ws;

    hipLaunchKernelGGL(prep_w, dim3(624), dim3(256), 0, stream, W1, W2, W3, W4, wp);
    hipLaunchKernelGGL(mlp_mfma, dim3(M_TOTAL / 256), dim3(256), 0, stream,
                       x, wp, b1, b2, b3, b4, out);
}

// Round 12
// 54.215 us; speedup vs baseline: 1.0645x; 1.0645x over previous
//
#include <hip/hip_runtime.h>

// Fully-fused 4-layer MLP via f16 MFMA (fp32 accumulate), transposed problem
// G = H^T: activations live in registers across all layers (B operand).
// R12 = R5's proven skeleton (16 KB strips, 3-deep pipeline, counted vmcnt
// barriers, permlane32_swap repack, direct L4 stores) scaled to 8-wave
// (512-thread) blocks: halves redundant weight-stage L2 traffic and gives
// 16 waves/CU. __launch_bounds__(512,2): 2 blocks/CU * 8 waves = 4 waves/EU
// -> 128-VGPR budget (S=1 needs ~90, no spill; R7's 64-reg trap avoided).

typedef _Float16 half_t;
typedef _Float16 half8 __attribute__((ext_vector_type(8)));
typedef float f32x16 __attribute__((ext_vector_type(16)));
typedef unsigned int uint4v __attribute__((ext_vector_type(4)));
typedef int int2v __attribute__((ext_vector_type(2)));

#define M_TOTAL (64*2048)

// ---------------- prep kernel ----------------
// Strip-ordered fragment layout (halves), 512 halves per fragment-block:
//   L1: blocks 0..7     (strip 0: all 8 nt, ks=0, K padded 13->16)
//   L2: blocks 8..135   (strips 1..8:  nt*16 + ks)
//   L3: blocks 136..263 (strips 9..16)
//   L4: blocks 264..311 (strips 17..19, N padded 80->96)
// Within a block: wp[blk*512 + lane*8 + j] = W[ks*16 + (lane>>5)*8 + j][nt*32 + (lane&31)]
__global__ void prep_w(const float* __restrict__ W1, const float* __restrict__ W2,
                       const float* __restrict__ W3, const float* __restrict__ W4,
                       half_t* __restrict__ wp) {
    int tid = blockIdx.x * 256 + threadIdx.x;
    if (tid >= 312 * 512) return;
    int blk = tid >> 9, r = tid & 511;
    int lane = r >> 3, j = r & 7;
    const float* W; int K, N, nt, ks;
    if (blk < 8)        { W = W1; K = 13;  N = 256; nt = blk;              ks = 0; }
    else if (blk < 136) { W = W2; K = 256; N = 256; nt = (blk-8) >> 4;     ks = (blk-8) & 15; }
    else if (blk < 264) { W = W3; K = 256; N = 256; nt = (blk-136) >> 4;   ks = (blk-136) & 15; }
    else                { W = W4; K = 256; N = 80;  nt = (blk-264) >> 4;   ks = (blk-264) & 15; }
    int k = ks * 16 + (lane >> 5) * 8 + j;
    int n = nt * 32 + (lane & 31);
    float v = (k < K && n < N) ? W[k * N + n] : 0.f;
    wp[tid] = (half_t)v;
}

// ---------------- main kernel ----------------

__device__ __forceinline__ unsigned int pkrtz(float a, float b) {
    auto p = __builtin_amdgcn_cvt_pkrtz(a, b);
    return __builtin_bit_cast(unsigned int, p);
}

typedef const __attribute__((address_space(1))) unsigned int guint_t;
typedef __attribute__((address_space(3))) unsigned int luint_t;

// Stage `bytes` (multiple of 8192) from g into LDS l. 512 threads x 16 B.
__device__ __forceinline__ void stage_strip(const half_t* __restrict__ g,
                                            half_t* l, int bytes, int tid) {
    const char* gc = (const char*)g;
    char* lc = (char*)l;
    const int go = tid * 16;             // per-lane global offset
    const int lo = (tid >> 6) << 10;     // wave-uniform LDS offset (wave*1024)
#pragma unroll
    for (int r = 0; r < bytes; r += 8192) {
        __builtin_amdgcn_global_load_lds((guint_t*)(gc + r + go),
                                         (luint_t*)(lc + r + lo), 16, 0, 0);
    }
}

// strip index -> offset in wp (halves); folds at compile time after unroll
__device__ __forceinline__ int strip_off(int s) {
    if (s == 0)  return 0;
    if (s <= 8)  return (8   + (s - 1)  * 16) * 512;
    if (s <= 16) return (136 + (s - 9)  * 16) * 512;
    return (264 + (s - 17) * 16) * 512;
}

// Counted-vmcnt pipeline barrier: keep newest stage's loads in flight.
#define PIPE_BAR(Nstr) do {                                   \
    asm volatile("s_waitcnt vmcnt(" Nstr ")" ::: "memory");   \
    __builtin_amdgcn_sched_barrier(0);                        \
    __builtin_amdgcn_s_barrier();                             \
    __builtin_amdgcn_sched_barrier(0);                        \
} while (0)

// One 32-feature output tile: K = NKS*16 from LDS strip, repack into 2 B-words.
template <int NKS, bool RELU>
__device__ __forceinline__ void dense_tile(const half_t* astrip,
                                           const unsigned int (&Bin)[16][4],
                                           unsigned int (*Bout)[4],
                                           const float* biasnt, int lane, bool hi)
{
    f32x16 acc = {};
    __builtin_amdgcn_s_setprio(1);
#pragma unroll
    for (int ks = 0; ks < NKS; ++ks) {
        half8 a = *(const half8*)(astrip + ((ks * 64 + lane) << 3));
        uint4v bw = { Bin[ks][0], Bin[ks][1], Bin[ks][2], Bin[ks][3] };
        acc = __builtin_amdgcn_mfma_f32_32x32x16_f16(a, __builtin_bit_cast(half8, bw),
                                                     acc, 0, 0, 0);
    }
    __builtin_amdgcn_s_setprio(0);
#pragma unroll
    for (int s = 0; s < 2; ++s) {
        float v[8];
#pragma unroll
        for (int q = 0; q < 8; ++q) {
            // C row = (reg&3) + 8*(reg>>2) + 4*(lane>=32), reg = 8s+q
            int f = (q & 3) + 8 * (q >> 2) + (hi ? 4 : 0);
            float t = acc[8 * s + q] + biasnt[16 * s + f];
            v[q] = RELU ? fmaxf(t, 0.f) : t;
        }
        unsigned int P0 = pkrtz(v[0], v[1]);   // lo:(0,1)  hi:(4,5)
        unsigned int P1 = pkrtz(v[2], v[3]);   // lo:(2,3)  hi:(6,7)
        unsigned int P2 = pkrtz(v[4], v[5]);   // lo:(8,9)  hi:(12,13)
        unsigned int P3 = pkrtz(v[6], v[7]);   // lo:(10,11) hi:(14,15)
        // One swap fills two B-words: word0=[P0.lo|P2.lo], word2=[P0.hi|P2.hi]
        int2v r02 = __builtin_amdgcn_permlane32_swap((int)P0, (int)P2, false, false);
        int2v r13 = __builtin_amdgcn_permlane32_swap((int)P1, (int)P3, false, false);
        Bout[s][0] = (unsigned int)r02.x;
        Bout[s][1] = (unsigned int)r13.x;
        Bout[s][2] = (unsigned int)r02.y;
        Bout[s][3] = (unsigned int)r13.y;
    }
}

// L4 tile: 32 features, direct global stores from the C fragment.
__device__ __forceinline__ void out_tile(const half_t* astrip,
                                         const unsigned int (&Bin)[16][4],
                                         const float* biasnt, float* __restrict__ out,
                                         int m0, int nt, int lane, bool hi)
{
    f32x16 acc = {};
    __builtin_amdgcn_s_setprio(1);
#pragma unroll
    for (int ks = 0; ks < 16; ++ks) {
        half8 a = *(const half8*)(astrip + ((ks * 64 + lane) << 3));
        uint4v bw = { Bin[ks][0], Bin[ks][1], Bin[ks][2], Bin[ks][3] };
        acc = __builtin_amdgcn_mfma_f32_32x32x16_f16(a, __builtin_bit_cast(half8, bw),
                                                     acc, 0, 0, 0);
    }
    __builtin_amdgcn_s_setprio(0);
    float* orow = out + (long)(m0 + (lane & 31)) * 80 + nt * 32;
#pragma unroll
    for (int reg = 0; reg < 16; ++reg) {
        if (nt == 2 && (reg >> 2) >= 2) continue;   // f = 64+rr < 80 <=> rr < 16
        int rr = (reg & 3) + 8 * (reg >> 2) + (hi ? 4 : 0);
        orow[rr] = acc[reg] + biasnt[rr];
    }
}

__global__ __launch_bounds__(512, 2) void mlp_mfma(
    const float* __restrict__ x, const half_t* __restrict__ wp,
    const float* __restrict__ b1, const float* __restrict__ b2,
    const float* __restrict__ b3, const float* __restrict__ b4,
    float* __restrict__ out)
{
    __shared__ half_t wbuf[3][8192];     // 3-deep strip pipeline (3 x 16 KB)
    __shared__ float  bias_lds[864];     // b1|b2|b3 (256 each) | b4 (96, padded)

    const int tid  = threadIdx.x;
    const int lane = tid & 63;
    const bool hi  = lane >= 32;
    const int m0   = (blockIdx.x * 8 + (tid >> 6)) * 32;   // 32 samples per wave

    if (tid < 256) {
        bias_lds[tid] = b1[tid];
        bias_lds[256 + tid] = b2[tid];
        bias_lds[512 + tid] = b3[tid];
    } else if (tid < 352) {
        int t = tid - 256;
        bias_lds[768 + t] = (t < 80) ? b4[t] : 0.f;
    }

    stage_strip(wp + strip_off(0), wbuf[0], 8192, tid);    // L1 strip (8 KB)
    stage_strip(wp + strip_off(1), wbuf[1], 16384, tid);

    unsigned int BA[16][4], BB[16][4];

    // Layer-1 B fragment from fp32 x: lane holds x[m][k], k = (hi?8:0)+j
    {
        const float* xp = x + (long)(m0 + (lane & 31)) * 13;
        float xv[8];
        if (!hi) {
#pragma unroll
            for (int j = 0; j < 8; ++j) xv[j] = xp[j];
        } else {
#pragma unroll
            for (int j = 0; j < 5; ++j) xv[j] = xp[8 + j];
            xv[5] = xv[6] = xv[7] = 0.f;
        }
        BA[0][0] = pkrtz(xv[0], xv[1]);
        BA[0][1] = pkrtz(xv[2], xv[3]);
        BA[0][2] = pkrtz(xv[4], xv[5]);
        BA[0][3] = pkrtz(xv[6], xv[7]);
    }

    __syncthreads();   // phase-0 entry: bias + strips 0,1 resident

    // ---- Phase 0 / L1: strip 0 (8 nt-blocks), 13->256 ----
    stage_strip(wp + strip_off(2), wbuf[2], 16384, tid);
#pragma unroll
    for (int nt = 0; nt < 8; ++nt)
        dense_tile<1, true>(&wbuf[0][nt * 512], BA, &BB[2 * nt],
                            bias_lds + nt * 32, lane, hi);

    // ---- Phases 1..8 / L2: strips 1..8, 256->256 ----
#pragma unroll
    for (int i = 0; i < 8; ++i) {
        const int k = 1 + i;
        PIPE_BAR("2");                              // strip k landed; k+1 in flight
        stage_strip(wp + strip_off(k + 2), wbuf[(k + 2) % 3], 16384, tid);
        dense_tile<16, true>(&wbuf[k % 3][0], BB, &BA[2 * i],
                             bias_lds + 256 + i * 32, lane, hi);
    }

    // ---- Phases 9..16 / L3: strips 9..16, 256->256 ----
#pragma unroll
    for (int i = 0; i < 8; ++i) {
        const int k = 9 + i;
        PIPE_BAR("2");
        stage_strip(wp + strip_off(k + 2), wbuf[(k + 2) % 3], 16384, tid);
        dense_tile<16, true>(&wbuf[k % 3][0], BA, &BB[2 * i],
                             bias_lds + 512 + i * 32, lane, hi);
    }

    // ---- Phases 17..19 / L4: strips 17..19, 256->80, direct stores ----
#pragma unroll
    for (int i = 0; i < 3; ++i) {
        const int k = 17 + i;
        if (i < 2) PIPE_BAR("2");                   // over-waits stores; safe
        else       PIPE_BAR("0");                   // last strip must be fully landed
        if (i == 0) stage_strip(wp + strip_off(19), wbuf[19 % 3], 16384, tid);
        out_tile(&wbuf[k % 3][0], BB, bias_lds + 768 + i * 32, out, m0, i, lane, hi);
    }
}

// ---------------- launch ----------------

extern "C" void kernel_launch(void* const* d_in, const int* in_sizes, int n_in,
                              void* d_out, int out_size, void* d_ws, size_t ws_size,
                              hipStream_t stream) {
    const float* x  = (const float*)d_in[0];
    const float* W1 = (const float*)d_in[1];
    const float* b1 = (const float*)d_in[2];
    const float* W2 = (const float*)d_in[3];
    const float* b2 = (const float*)d_in[4];
    const float* W3 = (const float*)d_in[5];
    const float* b3 = (const float*)d_in[6];
    const float* W4 = (const float*)d_in[7];
    const float* b4 = (const float*)d_in[8];
    float* out = (float*)d_out;

    half_t* wp = (half_t*)d_ws;

    hipLaunchKernelGGL(prep_w, dim3(624), dim3(256), 0, stream, W1, W2, W3, W4, wp);
    hipLaunchKernelGGL(mlp_mfma, dim3(M_TOTAL / 256), dim3(512), 0, stream,
                       x, wp, b1, b2, b3, b4, out);
}